// Round 12
// baseline (211.613 us; speedup 1.0000x reference)
//
#include <hip/hip_runtime.h>
#include <stdint.h>

#define NB 2
#define NL 2048
#define NH 16
#define ND 64
// out: [B,H,L,S] f32, S = NL

typedef __attribute__((ext_vector_type(8))) short short8;
typedef __attribute__((ext_vector_type(4))) float f32x4;
typedef __attribute__((ext_vector_type(4))) unsigned short ushort4v;

__device__ __forceinline__ unsigned short f2bf_rne(float x) {
    union { float f; unsigned int u; } v; v.f = x;
    unsigned int r = v.u + 0x7fffu + ((v.u >> 16) & 1u);
    return (unsigned short)(r >> 16);
}
__device__ __forceinline__ float bf2f(unsigned short b) {
    union { unsigned int u; float f; } v; v.u = ((unsigned int)b) << 16;
    return v.f;
}

// ---------------- Kernel PRE: fused proj-q | proj-k | ksum partials
// blocks 0..511: proj query -> qbh/qbl ; 512..1023: proj key -> kbh/kbl ;
// 1024..1535: ksum partials (f64, fixed order).
// Panel store swizzle: 4-elem group at e4 goes to e4 ^ ((row&7)<<3).
__global__ __launch_bounds__(256) void pre_kernel(const float* __restrict__ query,
                                                  const float* __restrict__ key,
                                                  const float* __restrict__ Wq,
                                                  const float* __restrict__ Wk,
                                                  unsigned short* __restrict__ qbh,
                                                  unsigned short* __restrict__ qbl,
                                                  unsigned short* __restrict__ kbh,
                                                  unsigned short* __restrict__ kbl,
                                                  double* __restrict__ part) {
    __shared__ __align__(16) char lds_raw[16384 + 34816];  // Wlds | xs
    const int blk = blockIdx.x;
    const int t = threadIdx.x;

    if (blk < 1024) {
        const bool isq = blk < 512;
        const int pb = isq ? blk : blk - 512;
        const float* x = isq ? query : key;
        const float* W = isq ? Wq : Wk;
        unsigned short* ph = isq ? qbh : kbh;
        unsigned short* pl = isq ? qbl : kbl;
        float* Wlds = (float*)lds_raw;                 // [d][e] 16KB
        float* xs = (float*)(lds_raw + 16384);         // [r][d] stride 68

        const int lc = pb & 15;
        const int h = (pb >> 4) & 15;
        const int b = pb >> 8;
        const int l0 = lc * 128;

        {
            const float4* src = (const float4*)(W + (size_t)h * ND * ND);
#pragma unroll
            for (int i = 0; i < 4; ++i)
                ((float4*)Wlds)[t + 256 * i] = src[t + 256 * i];
        }
        {
#pragma unroll
            for (int i = 0; i < 8; ++i) {
                const int idx = t + 256 * i;  // 0..2047
                const int r = idx >> 4, c = idx & 15;
                const float4 v = *(const float4*)(x + (((size_t)b * NL + l0 + r) * NH + h) * ND + c * 4);
                *(float4*)&xs[r * 68 + c * 4] = v;
            }
        }
        __syncthreads();

        const int e4 = (t & 15) * 4;
        const int rg = t >> 4;  // 0..15
        float acc[8][4] = {};
        for (int d = 0; d < ND; ++d) {
            const float4 w4 = *(const float4*)&Wlds[d * ND + e4];
#pragma unroll
            for (int it = 0; it < 8; ++it) {
                const float xv = xs[(rg + it * 16) * 68 + d];
                acc[it][0] += xv * w4.x; acc[it][1] += xv * w4.y;
                acc[it][2] += xv * w4.z; acc[it][3] += xv * w4.w;
            }
        }

        unsigned short* phh = ph + ((size_t)(b * NH + h) * NL + l0) * ND;
        unsigned short* pll = pl + ((size_t)(b * NH + h) * NL + l0) * ND;
#pragma unroll
        for (int it = 0; it < 8; ++it) {
            const int r = rg + it * 16;
            const int ep = e4 ^ ((r & 7) << 3);
            ushort4v hv, lv;
#pragma unroll
            for (int j = 0; j < 4; ++j) {
                const unsigned short hb = f2bf_rne(acc[it][j]);
                hv[j] = hb;
                lv[j] = f2bf_rne(acc[it][j] - bf2f(hb));
            }
            *(ushort4v*)&phh[(size_t)r * ND + ep] = hv;
            *(ushort4v*)&pll[(size_t)r * ND + ep] = lv;
        }
    } else {
        // ---- ksum partials path (identical arithmetic/order to R7)
        double (*red)[64] = (double(*)[64])lds_raw;
        const int blk2 = blk - 1024;  // bh*16 + chunk
        const int chunk = blk2 & 15, bh = blk2 >> 4;
        const int b = bh >> 4, h = bh & 15;
        const int e = t & 63, sub = t >> 6;
        const float* base = key + ((size_t)b * NL * NH + h) * ND + e;
        double acc = 0.0;
        const int s0 = chunk * 128 + sub * 32;
        for (int s = s0; s < s0 + 32; ++s)
            acc += (double)base[(size_t)s * (NH * ND)];
        red[sub][e] = acc;
        __syncthreads();
        if (t < 64) {
            const double s2 = red[0][t] + red[1][t] + red[2][t] + red[3][t];
            part[(size_t)blk2 * 64 + t] = s2;
        }
    }
}

// ---------------- Kernel D: fused prep+den.
// Each block (bh, lchunk) redundantly computes v[bh] = Wq.(Wk^T.xsum) in f64
// (identical order to the old prep_kernel), then its 256 invden values.
__global__ __launch_bounds__(256) void den_kernel(const float* __restrict__ xq,
                                                  const double* __restrict__ part,
                                                  const float* __restrict__ Wq,
                                                  const float* __restrict__ Wk,
                                                  float* __restrict__ invden) {
    __shared__ double xs[ND], ks[ND], vs[ND];
    const int bh = blockIdx.x;
    const int b = bh >> 4, h = bh & 15;
    const int t = threadIdx.x;
    if (t < 64) {
        double a = 0.0;
#pragma unroll
        for (int c = 0; c < 16; ++c) a += part[((size_t)bh * 16 + c) * 64 + t];
        xs[t] = a;
    }
    __syncthreads();
    if (t < 64) {
        double acc = 0.0;
        const float* wk = Wk + (size_t)h * ND * ND + t;  // column t
        for (int d = 0; d < ND; ++d) acc += xs[d] * (double)wk[(size_t)d * ND];
        ks[t] = acc;
    }
    __syncthreads();
    if (t < 64) {
        double acc = 0.0;
        const float* wq = Wq + (size_t)h * ND * ND + (size_t)t * ND;  // row t
        for (int e = 0; e < ND; ++e) acc += (double)wq[e] * ks[e];
        vs[t] = acc;
    }
    __syncthreads();
    const int l = blockIdx.y * 256 + t;
    const float* xp = xq + (((size_t)b * NL + l) * NH + h) * ND;
    double acc = 0.0;
#pragma unroll 8
    for (int d = 0; d < ND; ++d) acc += (double)xp[d] * vs[d];
    invden[(size_t)bh * NL + l] = (float)(1.0 / acc);
}

// ---------------- Kernel E: attn — T-G build: software-pipelined q loads.
// R11 structure (K panels in 32KB LDS staged once, single barrier, 4 l-tiles,
// q direct from L2-hot panels) BUT q loads for half-tile H+1 are issued BEFORE
// half-tile H's MFMAs, so the s_waitcnt before MFMAs is a counted vmcnt that
// never drains the store queue (loads+stores share vmcnt on CDNA).
__global__ __launch_bounds__(256, 4) void attn_kernel(const unsigned short* __restrict__ qbh,
                                                      const unsigned short* __restrict__ qbl,
                                                      const unsigned short* __restrict__ kbh,
                                                      const unsigned short* __restrict__ kbl,
                                                      const float* __restrict__ invden,
                                                      float* __restrict__ out) {
    __shared__ unsigned short smem[2 * 128 * 64];  // kh|kl, 16KB each, linear
    const int lg = blockIdx.x;           // l-group 0..3 (4 tiles each)
    const int s0 = blockIdx.y * 128;
    const int bh = blockIdx.z;
    const int t = threadIdx.x;
    const int w = t >> 6, ln = t & 63;

    // ---- stage K panels once: 2 arrays * 4 insts per wave (1KB each)
    {
        const size_t pan = (size_t)bh * NL * ND;
        const unsigned short* srcs[2] = {kbh + pan + (size_t)s0 * ND,
                                         kbl + pan + (size_t)s0 * ND};
#pragma unroll
        for (int arr = 0; arr < 2; ++arr) {
            const unsigned short* s = srcs[arr] + w * 2048 + ln * 8;
            unsigned short* d = smem + arr * 8192 + w * 2048;
#pragma unroll
            for (int u = 0; u < 4; ++u) {
                __builtin_amdgcn_global_load_lds((const __attribute__((address_space(1))) unsigned int*)(s + u * 512),
                                                 (__attribute__((address_space(3))) unsigned int*)(d + u * 512),
                                                 16, 0, 0);
            }
        }
    }
    __syncthreads();  // the ONLY barrier

    const int wr = w >> 1, wc = w & 1;
    const int fr = ln & 15, g = ln >> 4;
    const int swz = (fr & 7) << 4;
    const int cofs0 = (g << 4) ^ swz;
    const int cofs1 = (64 | (g << 4)) ^ swz;
    const char* sb = (const char*)smem;
    const char* qh_pb = (const char*)(qbh + (size_t)bh * NL * ND);
    const char* ql_pb = (const char*)(qbl + (size_t)bh * NL * ND);
    const float* invb = invden + (size_t)bh * NL;

    // half-tile ht (0..7): rows lbase(ht) = lg*512 + (ht>>1)*128 + wc*64 + (ht&1)*32 + fr
    // ping-pong fragment sets; ALL indices compile-time constant after unroll.
    short8 qf[2][2][2][2];  // [set][j][hi/lo][kc]
    float invv[2][2];       // [set][j]

    {   // prologue: load half-tile 0 into set 0
        const int lb = lg * 512 + wc * 64 + fr;
#pragma unroll
        for (int j = 0; j < 2; ++j) {
            const size_t roff = (size_t)(lb + j * 16) * 128;
            qf[0][j][0][0] = *(const short8*)(qh_pb + roff + cofs0);
            qf[0][j][0][1] = *(const short8*)(qh_pb + roff + cofs1);
            qf[0][j][1][0] = *(const short8*)(ql_pb + roff + cofs0);
            qf[0][j][1][1] = *(const short8*)(ql_pb + roff + cofs1);
            invv[0][j] = invb[lb + j * 16];
        }
    }

#pragma unroll
    for (int ht = 0; ht < 8; ++ht) {
        const int cur = ht & 1, nxt = cur ^ 1;
        if (ht < 7) {  // issue NEXT half-tile's loads before current MFMAs
            const int h2 = ht + 1;
            const int lb = lg * 512 + (h2 >> 1) * 128 + wc * 64 + (h2 & 1) * 32 + fr;
#pragma unroll
            for (int j = 0; j < 2; ++j) {
                const size_t roff = (size_t)(lb + j * 16) * 128;
                qf[nxt][j][0][0] = *(const short8*)(qh_pb + roff + cofs0);
                qf[nxt][j][0][1] = *(const short8*)(qh_pb + roff + cofs1);
                qf[nxt][j][1][0] = *(const short8*)(ql_pb + roff + cofs0);
                qf[nxt][j][1][1] = *(const short8*)(ql_pb + roff + cofs1);
                invv[nxt][j] = invb[lb + j * 16];
            }
        }
        const int lbc = lg * 512 + (ht >> 1) * 128 + wc * 64 + (ht & 1) * 32 + fr;
#pragma unroll
        for (int i = 0; i < 4; ++i) {
            const int arow = wr * 64 + i * 16 + fr;
            const short8 kh0 = *(const short8*)(sb + arow * 128 + cofs0);
            const short8 kh1 = *(const short8*)(sb + arow * 128 + cofs1);
            const short8 kl0 = *(const short8*)(sb + 16384 + arow * 128 + cofs0);
            const short8 kl1 = *(const short8*)(sb + 16384 + arow * 128 + cofs1);
#pragma unroll
            for (int j = 0; j < 2; ++j) {
                f32x4 a = (f32x4){0.f, 0.f, 0.f, 0.f};
                a = __builtin_amdgcn_mfma_f32_16x16x32_bf16(kh0, qf[cur][j][0][0], a, 0, 0, 0);
                a = __builtin_amdgcn_mfma_f32_16x16x32_bf16(kh0, qf[cur][j][1][0], a, 0, 0, 0);
                a = __builtin_amdgcn_mfma_f32_16x16x32_bf16(kl0, qf[cur][j][0][0], a, 0, 0, 0);
                a = __builtin_amdgcn_mfma_f32_16x16x32_bf16(kh1, qf[cur][j][0][1], a, 0, 0, 0);
                a = __builtin_amdgcn_mfma_f32_16x16x32_bf16(kh1, qf[cur][j][1][1], a, 0, 0, 0);
                a = __builtin_amdgcn_mfma_f32_16x16x32_bf16(kl1, qf[cur][j][0][1], a, 0, 0, 0);
                const float inv = invv[cur][j];
                f32x4 vv = a;
                vv[0] *= inv; vv[1] *= inv; vv[2] *= inv; vv[3] *= inv;
                *(f32x4*)(out + ((size_t)bh * NL + lbc + j * 16) * NL + s0 + wr * 64 + g * 4 + i * 16) = vv;
            }
        }
    }
}

extern "C" void kernel_launch(void* const* d_in, const int* in_sizes, int n_in,
                              void* d_out, int out_size, void* d_ws, size_t ws_size,
                              hipStream_t stream) {
    const float* query = (const float*)d_in[0];  // [B,L,H,D]
    const float* key   = (const float*)d_in[1];  // [B,L,H,D]
    const float* Wq    = (const float*)d_in[2];  // [H,D,D]
    const float* Wk    = (const float*)d_in[3];  // [H,D,D]
    float* out = (float*)d_out;                  // [B,H,L,S]

    const size_t npan = (size_t)NB * NH * NL * ND;  // 4.19M elems
    char* ws = (char*)d_ws;
    unsigned short* qbh = (unsigned short*)(ws);
    unsigned short* qbl = (unsigned short*)(ws + 1 * npan * 2);
    unsigned short* kbh = (unsigned short*)(ws + 2 * npan * 2);
    unsigned short* kbl = (unsigned short*)(ws + 3 * npan * 2);
    double* part  = (double*)(ws + 4 * npan * 2);                  // 512*64 f64 = 256KB
    float* invden = (float*)(ws + 4 * npan * 2 + 262144);          // 32*2048 f32

    pre_kernel<<<1536, 256, 0, stream>>>(query, key, Wq, Wk, qbh, qbl, kbh, kbl, part);
    den_kernel<<<dim3(NB * NH, NL / 256), 256, 0, stream>>>(query, part, Wq, Wk, invden);
    attn_kernel<<<dim3(4, 16, NB * NH), 256, 0, stream>>>(qbh, qbl, kbh, kbl, invden, out);
}

// Round 13
// 185.919 us; speedup vs baseline: 1.1382x; 1.1382x over previous
//
#include <hip/hip_runtime.h>
#include <stdint.h>

#define NB 2
#define NL 2048
#define NH 16
#define ND 64
// out: [B,H,L,S] f32, S = NL

typedef __attribute__((ext_vector_type(8))) short short8;
typedef __attribute__((ext_vector_type(4))) float f32x4;
typedef __attribute__((ext_vector_type(4))) unsigned short ushort4v;

__device__ __forceinline__ unsigned short f2bf_rne(float x) {
    union { float f; unsigned int u; } v; v.f = x;
    unsigned int r = v.u + 0x7fffu + ((v.u >> 16) & 1u);
    return (unsigned short)(r >> 16);
}
__device__ __forceinline__ float bf2f(unsigned short b) {
    union { unsigned int u; float f; } v; v.u = ((unsigned int)b) << 16;
    return v.f;
}

// ---------------- Kernel PRE: fused proj-q | proj-k | ksum partials (R11 verbatim)
__global__ __launch_bounds__(256) void pre_kernel(const float* __restrict__ query,
                                                  const float* __restrict__ key,
                                                  const float* __restrict__ Wq,
                                                  const float* __restrict__ Wk,
                                                  unsigned short* __restrict__ qbh,
                                                  unsigned short* __restrict__ qbl,
                                                  unsigned short* __restrict__ kbh,
                                                  unsigned short* __restrict__ kbl,
                                                  double* __restrict__ part) {
    __shared__ __align__(16) char lds_raw[16384 + 34816];  // Wlds | xs
    const int blk = blockIdx.x;
    const int t = threadIdx.x;

    if (blk < 1024) {
        const bool isq = blk < 512;
        const int pb = isq ? blk : blk - 512;
        const float* x = isq ? query : key;
        const float* W = isq ? Wq : Wk;
        unsigned short* ph = isq ? qbh : kbh;
        unsigned short* pl = isq ? qbl : kbl;
        float* Wlds = (float*)lds_raw;                 // [d][e] 16KB
        float* xs = (float*)(lds_raw + 16384);         // [r][d] stride 68

        const int lc = pb & 15;
        const int h = (pb >> 4) & 15;
        const int b = pb >> 8;
        const int l0 = lc * 128;

        {
            const float4* src = (const float4*)(W + (size_t)h * ND * ND);
#pragma unroll
            for (int i = 0; i < 4; ++i)
                ((float4*)Wlds)[t + 256 * i] = src[t + 256 * i];
        }
        {
#pragma unroll
            for (int i = 0; i < 8; ++i) {
                const int idx = t + 256 * i;  // 0..2047
                const int r = idx >> 4, c = idx & 15;
                const float4 v = *(const float4*)(x + (((size_t)b * NL + l0 + r) * NH + h) * ND + c * 4);
                *(float4*)&xs[r * 68 + c * 4] = v;
            }
        }
        __syncthreads();

        const int e4 = (t & 15) * 4;
        const int rg = t >> 4;  // 0..15
        float acc[8][4] = {};
        for (int d = 0; d < ND; ++d) {
            const float4 w4 = *(const float4*)&Wlds[d * ND + e4];
#pragma unroll
            for (int it = 0; it < 8; ++it) {
                const float xv = xs[(rg + it * 16) * 68 + d];
                acc[it][0] += xv * w4.x; acc[it][1] += xv * w4.y;
                acc[it][2] += xv * w4.z; acc[it][3] += xv * w4.w;
            }
        }

        unsigned short* phh = ph + ((size_t)(b * NH + h) * NL + l0) * ND;
        unsigned short* pll = pl + ((size_t)(b * NH + h) * NL + l0) * ND;
#pragma unroll
        for (int it = 0; it < 8; ++it) {
            const int r = rg + it * 16;
            const int ep = e4 ^ ((r & 7) << 3);
            ushort4v hv, lv;
#pragma unroll
            for (int j = 0; j < 4; ++j) {
                const unsigned short hb = f2bf_rne(acc[it][j]);
                hv[j] = hb;
                lv[j] = f2bf_rne(acc[it][j] - bf2f(hb));
            }
            *(ushort4v*)&phh[(size_t)r * ND + ep] = hv;
            *(ushort4v*)&pll[(size_t)r * ND + ep] = lv;
        }
    } else {
        double (*red)[64] = (double(*)[64])lds_raw;
        const int blk2 = blk - 1024;  // bh*16 + chunk
        const int chunk = blk2 & 15, bh = blk2 >> 4;
        const int b = bh >> 4, h = bh & 15;
        const int e = t & 63, sub = t >> 6;
        const float* base = key + ((size_t)b * NL * NH + h) * ND + e;
        double acc = 0.0;
        const int s0 = chunk * 128 + sub * 32;
        for (int s = s0; s < s0 + 32; ++s)
            acc += (double)base[(size_t)s * (NH * ND)];
        red[sub][e] = acc;
        __syncthreads();
        if (t < 64) {
            const double s2 = red[0][t] + red[1][t] + red[2][t] + red[3][t];
            part[(size_t)blk2 * 64 + t] = s2;
        }
    }
}

// ---------------- Kernel C: reduce partials; v[b,h,d] = Wq . (Wk^T . xsum)  (f64)
__global__ __launch_bounds__(64) void prep_kernel(const double* __restrict__ part,
                                                  const float* __restrict__ Wq,
                                                  const float* __restrict__ Wk,
                                                  double* __restrict__ v) {
    __shared__ double xs[ND], ks[ND];
    const int bh = blockIdx.x;
    const int h = bh & 15;
    const int t = threadIdx.x;  // 0..63
    {
        double a = 0.0;
#pragma unroll
        for (int c = 0; c < 16; ++c) a += part[((size_t)bh * 16 + c) * 64 + t];
        xs[t] = a;
    }
    __syncthreads();
    {
        double acc = 0.0;
        const float* wk = Wk + (size_t)h * ND * ND + t;  // column t
        for (int d = 0; d < ND; ++d) acc += xs[d] * (double)wk[(size_t)d * ND];
        ks[t] = acc;
    }
    __syncthreads();
    {
        double acc = 0.0;
        const float* wq = Wq + (size_t)h * ND * ND + (size_t)t * ND;  // row t
        for (int e = 0; e < ND; ++e) acc += (double)wq[e] * ks[e];
        v[(size_t)bh * ND + t] = acc;
    }
}

// ---------------- Kernel D: invden[b,h,l] = 1 / (x_q . v)  (f64 exact)
__global__ __launch_bounds__(256) void den_kernel(const float* __restrict__ xq,
                                                  const double* __restrict__ v,
                                                  float* __restrict__ invden) {
    __shared__ double vs[ND];
    const int bh = blockIdx.x;
    const int b = bh >> 4, h = bh & 15;
    const int t = threadIdx.x;
    if (t < 64) vs[t] = v[(size_t)bh * ND + t];
    __syncthreads();
    const int l = blockIdx.y * 256 + t;
    const float* xp = xq + (((size_t)b * NL + l) * NH + h) * ND;
    double acc = 0.0;
#pragma unroll 8
    for (int d = 0; d < ND; ++d) acc += (double)xp[d] * vs[d];
    invden[(size_t)bh * NL + l] = (float)(1.0 / acc);
}

// ---------------- Kernel E: attn — T-H build: strip-persistent, minimal traffic.
// Block = (bh, 256 l-rows x ALL s). 256 blocks = 1/CU, 8 waves x 32 rows.
// Q frags in registers (loaded once). K streamed via 32KB LDS dbuf in 32 chunks
// of 64 s-rows; counted s_waitcnt vmcnt(8) releases each chunk WITHOUT draining
// the 8 in-flight output stores. Read traffic 537->150MB vs tiled builds.
__global__ __launch_bounds__(512, 1) void attn_kernel(const unsigned short* __restrict__ qbh,
                                                      const unsigned short* __restrict__ qbl,
                                                      const unsigned short* __restrict__ kbh,
                                                      const unsigned short* __restrict__ kbl,
                                                      const float* __restrict__ invden,
                                                      float* __restrict__ out) {
    __shared__ unsigned short kbuf[2][2][64 * 64];  // [buf][kh/kl][s_local*64+e] = 32KB
    const int strip = blockIdx.x;        // 0..7
    const int bh = blockIdx.y;           // 0..31
    const int l0 = strip * 256;
    const int t = threadIdx.x;
    const int w = t >> 6, ln = t & 63;   // 8 waves
    const int fr = ln & 15, g = ln >> 4;
    const int swz = (fr & 7) << 4;
    const int cofs0 = (g << 4) ^ swz;
    const int cofs1 = (64 | (g << 4)) ^ swz;

    const size_t pan = (size_t)bh * NL * ND;
    const unsigned short* kh_p = kbh + pan;
    const unsigned short* kl_p = kbl + pan;
    const char* qh_pb = (const char*)(qbh + pan);
    const char* ql_pb = (const char*)(qbl + pan);
    const int lbase = l0 + w * 32;

    // ---- q fragments for this wave's 32 rows: registers, loaded once
    short8 qf00, qf01, qf10, qf11, qg00, qg01, qg10, qg11;  // [jl][hi/lo][kc] flattened
    {
        const size_t r0 = (size_t)(lbase + fr) * 128;
        const size_t r1 = (size_t)(lbase + 16 + fr) * 128;
        qf00 = *(const short8*)(qh_pb + r0 + cofs0);  // jl0 hi kc0
        qf01 = *(const short8*)(qh_pb + r0 + cofs1);  // jl0 hi kc1
        qf10 = *(const short8*)(ql_pb + r0 + cofs0);  // jl0 lo kc0
        qf11 = *(const short8*)(ql_pb + r0 + cofs1);  // jl0 lo kc1
        qg00 = *(const short8*)(qh_pb + r1 + cofs0);  // jl1 hi kc0
        qg01 = *(const short8*)(qh_pb + r1 + cofs1);
        qg10 = *(const short8*)(ql_pb + r1 + cofs0);
        qg11 = *(const short8*)(ql_pb + r1 + cofs1);
    }
    const float inv0 = invden[(size_t)bh * NL + lbase + fr];
    const float inv1 = invden[(size_t)bh * NL + lbase + 16 + fr];

    // ---- stage chunk c (64 s-rows, kh+kl = 16KB) into kbuf[buf]: 2 gloads/wave
#define STAGE(c, buf)                                                                              \
    {                                                                                              \
        const int u0 = w * 2;                                                                      \
        _Pragma("unroll")                                                                          \
        for (int qq = 0; qq < 2; ++qq) {                                                           \
            const int u = u0 + qq;                                                                 \
            const unsigned short* src = (u < 8) ? (kh_p + (size_t)(c) * 4096 + u * 512 + ln * 8)   \
                                                : (kl_p + (size_t)(c) * 4096 + (u - 8) * 512 + ln * 8); \
            unsigned short* dst = (u < 8) ? &kbuf[buf][0][u * 512] : &kbuf[buf][1][(u - 8) * 512]; \
            __builtin_amdgcn_global_load_lds((const __attribute__((address_space(1))) unsigned int*)src, \
                                             (__attribute__((address_space(3))) unsigned int*)dst, \
                                             16, 0, 0);                                            \
        }                                                                                          \
    }

    STAGE(0, 0);
    asm volatile("s_waitcnt vmcnt(0)" ::: "memory");
    __builtin_amdgcn_sched_barrier(0);
    __builtin_amdgcn_s_barrier();

    for (int c = 0; c < 32; ++c) {
        const int cur = c & 1;
        if (c < 31) STAGE(c + 1, cur ^ 1);

        const char* kh_b = (const char*)kbuf[cur][0];
        const char* kl_b = (const char*)kbuf[cur][1];
#pragma unroll
        for (int is = 0; is < 4; ++is) {
            const int soff = (is * 16 + fr) * 128;
            const short8 kh0 = *(const short8*)(kh_b + soff + cofs0);
            const short8 kh1 = *(const short8*)(kh_b + soff + cofs1);
            const short8 kl0 = *(const short8*)(kl_b + soff + cofs0);
            const short8 kl1 = *(const short8*)(kl_b + soff + cofs1);
            // jl = 0
            {
                f32x4 a = (f32x4){0.f, 0.f, 0.f, 0.f};
                a = __builtin_amdgcn_mfma_f32_16x16x32_bf16(kh0, qf00, a, 0, 0, 0);
                a = __builtin_amdgcn_mfma_f32_16x16x32_bf16(kh0, qf10, a, 0, 0, 0);
                a = __builtin_amdgcn_mfma_f32_16x16x32_bf16(kl0, qf00, a, 0, 0, 0);
                a = __builtin_amdgcn_mfma_f32_16x16x32_bf16(kh1, qf01, a, 0, 0, 0);
                a = __builtin_amdgcn_mfma_f32_16x16x32_bf16(kh1, qf11, a, 0, 0, 0);
                a = __builtin_amdgcn_mfma_f32_16x16x32_bf16(kl1, qf01, a, 0, 0, 0);
                f32x4 vv = a;
                vv[0] *= inv0; vv[1] *= inv0; vv[2] *= inv0; vv[3] *= inv0;
                *(f32x4*)(out + ((size_t)bh * NL + lbase + fr) * NL + c * 64 + is * 16 + g * 4) = vv;
            }
            // jl = 1
            {
                f32x4 a = (f32x4){0.f, 0.f, 0.f, 0.f};
                a = __builtin_amdgcn_mfma_f32_16x16x32_bf16(kh0, qg00, a, 0, 0, 0);
                a = __builtin_amdgcn_mfma_f32_16x16x32_bf16(kh0, qg10, a, 0, 0, 0);
                a = __builtin_amdgcn_mfma_f32_16x16x32_bf16(kl0, qg00, a, 0, 0, 0);
                a = __builtin_amdgcn_mfma_f32_16x16x32_bf16(kh1, qg01, a, 0, 0, 0);
                a = __builtin_amdgcn_mfma_f32_16x16x32_bf16(kh1, qg11, a, 0, 0, 0);
                a = __builtin_amdgcn_mfma_f32_16x16x32_bf16(kl1, qg01, a, 0, 0, 0);
                f32x4 vv = a;
                vv[0] *= inv1; vv[1] *= inv1; vv[2] *= inv1; vv[3] *= inv1;
                *(f32x4*)(out + ((size_t)bh * NL + lbase + 16 + fr) * NL + c * 64 + is * 16 + g * 4) = vv;
            }
        }

        if (c < 31) {
            // release: this wave's 2 gloads (for c+1) are older than its 8 chunk
            // stores -> vmcnt(8) retires them (in-order decrement) while stores
            // stay in flight. No store drain in the main loop.
            asm volatile("s_waitcnt vmcnt(8)" ::: "memory");
            __builtin_amdgcn_sched_barrier(0);
            __builtin_amdgcn_s_barrier();
        }
    }
#undef STAGE
}

extern "C" void kernel_launch(void* const* d_in, const int* in_sizes, int n_in,
                              void* d_out, int out_size, void* d_ws, size_t ws_size,
                              hipStream_t stream) {
    const float* query = (const float*)d_in[0];  // [B,L,H,D]
    const float* key   = (const float*)d_in[1];  // [B,L,H,D]
    const float* Wq    = (const float*)d_in[2];  // [H,D,D]
    const float* Wk    = (const float*)d_in[3];  // [H,D,D]
    float* out = (float*)d_out;                  // [B,H,L,S]

    const size_t npan = (size_t)NB * NH * NL * ND;  // 4.19M elems
    char* ws = (char*)d_ws;
    unsigned short* qbh = (unsigned short*)(ws);
    unsigned short* qbl = (unsigned short*)(ws + 1 * npan * 2);
    unsigned short* kbh = (unsigned short*)(ws + 2 * npan * 2);
    unsigned short* kbl = (unsigned short*)(ws + 3 * npan * 2);
    double* part  = (double*)(ws + 4 * npan * 2);                  // 512*64 f64 = 256KB
    double* v     = (double*)(ws + 4 * npan * 2 + 262144);         // 32*64 f64
    float* invden = (float*)(ws + 4 * npan * 2 + 262144 + 16384);  // 32*2048 f32

    pre_kernel<<<1536, 256, 0, stream>>>(query, key, Wq, Wk, qbh, qbl, kbh, kbl, part);
    prep_kernel<<<NB * NH, 64, 0, stream>>>(part, Wq, Wk, v);
    den_kernel<<<dim3(NB * NH, NL / 256), 256, 0, stream>>>(query, v, invden);
    attn_kernel<<<dim3(8, NB * NH), 512, 0, stream>>>(qbh, qbl, kbh, kbl, invden, out);
}

// Round 14
// 184.014 us; speedup vs baseline: 1.1500x; 1.0104x over previous
//
#include <hip/hip_runtime.h>
#include <stdint.h>

#define NB 2
#define NL 2048
#define NH 16
#define ND 64
// out: [B,H,L,S] f32, S = NL

typedef __attribute__((ext_vector_type(8))) short short8;
typedef __attribute__((ext_vector_type(4))) float f32x4;
typedef __attribute__((ext_vector_type(4))) unsigned short ushort4v;

__device__ __forceinline__ unsigned short f2bf_rne(float x) {
    union { float f; unsigned int u; } v; v.f = x;
    unsigned int r = v.u + 0x7fffu + ((v.u >> 16) & 1u);
    return (unsigned short)(r >> 16);
}
__device__ __forceinline__ float bf2f(unsigned short b) {
    union { unsigned int u; float f; } v; v.u = ((unsigned int)b) << 16;
    return v.f;
}

// ---------------- Kernel PRE: fused proj-q | proj-k | ksum partials (R13 verbatim)
__global__ __launch_bounds__(256) void pre_kernel(const float* __restrict__ query,
                                                  const float* __restrict__ key,
                                                  const float* __restrict__ Wq,
                                                  const float* __restrict__ Wk,
                                                  unsigned short* __restrict__ qbh,
                                                  unsigned short* __restrict__ qbl,
                                                  unsigned short* __restrict__ kbh,
                                                  unsigned short* __restrict__ kbl,
                                                  double* __restrict__ part) {
    __shared__ __align__(16) char lds_raw[16384 + 34816];  // Wlds | xs
    const int blk = blockIdx.x;
    const int t = threadIdx.x;

    if (blk < 1024) {
        const bool isq = blk < 512;
        const int pb = isq ? blk : blk - 512;
        const float* x = isq ? query : key;
        const float* W = isq ? Wq : Wk;
        unsigned short* ph = isq ? qbh : kbh;
        unsigned short* pl = isq ? qbl : kbl;
        float* Wlds = (float*)lds_raw;                 // [d][e] 16KB
        float* xs = (float*)(lds_raw + 16384);         // [r][d] stride 68

        const int lc = pb & 15;
        const int h = (pb >> 4) & 15;
        const int b = pb >> 8;
        const int l0 = lc * 128;

        {
            const float4* src = (const float4*)(W + (size_t)h * ND * ND);
#pragma unroll
            for (int i = 0; i < 4; ++i)
                ((float4*)Wlds)[t + 256 * i] = src[t + 256 * i];
        }
        {
#pragma unroll
            for (int i = 0; i < 8; ++i) {
                const int idx = t + 256 * i;  // 0..2047
                const int r = idx >> 4, c = idx & 15;
                const float4 v = *(const float4*)(x + (((size_t)b * NL + l0 + r) * NH + h) * ND + c * 4);
                *(float4*)&xs[r * 68 + c * 4] = v;
            }
        }
        __syncthreads();

        const int e4 = (t & 15) * 4;
        const int rg = t >> 4;  // 0..15
        float acc[8][4] = {};
        for (int d = 0; d < ND; ++d) {
            const float4 w4 = *(const float4*)&Wlds[d * ND + e4];
#pragma unroll
            for (int it = 0; it < 8; ++it) {
                const float xv = xs[(rg + it * 16) * 68 + d];
                acc[it][0] += xv * w4.x; acc[it][1] += xv * w4.y;
                acc[it][2] += xv * w4.z; acc[it][3] += xv * w4.w;
            }
        }

        unsigned short* phh = ph + ((size_t)(b * NH + h) * NL + l0) * ND;
        unsigned short* pll = pl + ((size_t)(b * NH + h) * NL + l0) * ND;
#pragma unroll
        for (int it = 0; it < 8; ++it) {
            const int r = rg + it * 16;
            const int ep = e4 ^ ((r & 7) << 3);
            ushort4v hv, lv;
#pragma unroll
            for (int j = 0; j < 4; ++j) {
                const unsigned short hb = f2bf_rne(acc[it][j]);
                hv[j] = hb;
                lv[j] = f2bf_rne(acc[it][j] - bf2f(hb));
            }
            *(ushort4v*)&phh[(size_t)r * ND + ep] = hv;
            *(ushort4v*)&pll[(size_t)r * ND + ep] = lv;
        }
    } else {
        double (*red)[64] = (double(*)[64])lds_raw;
        const int blk2 = blk - 1024;  // bh*16 + chunk
        const int chunk = blk2 & 15, bh = blk2 >> 4;
        const int b = bh >> 4, h = bh & 15;
        const int e = t & 63, sub = t >> 6;
        const float* base = key + ((size_t)b * NL * NH + h) * ND + e;
        double acc = 0.0;
        const int s0 = chunk * 128 + sub * 32;
        for (int s = s0; s < s0 + 32; ++s)
            acc += (double)base[(size_t)s * (NH * ND)];
        red[sub][e] = acc;
        __syncthreads();
        if (t < 64) {
            const double s2 = red[0][t] + red[1][t] + red[2][t] + red[3][t];
            part[(size_t)blk2 * 64 + t] = s2;
        }
    }
}

// ---------------- Kernel D: fused prep+den (R12 verbatim, proven)
__global__ __launch_bounds__(256) void den_kernel(const float* __restrict__ xq,
                                                  const double* __restrict__ part,
                                                  const float* __restrict__ Wq,
                                                  const float* __restrict__ Wk,
                                                  float* __restrict__ invden) {
    __shared__ double xs[ND], ks[ND], vs[ND];
    const int bh = blockIdx.x;
    const int b = bh >> 4, h = bh & 15;
    const int t = threadIdx.x;
    if (t < 64) {
        double a = 0.0;
#pragma unroll
        for (int c = 0; c < 16; ++c) a += part[((size_t)bh * 16 + c) * 64 + t];
        xs[t] = a;
    }
    __syncthreads();
    if (t < 64) {
        double acc = 0.0;
        const float* wk = Wk + (size_t)h * ND * ND + t;  // column t
        for (int d = 0; d < ND; ++d) acc += xs[d] * (double)wk[(size_t)d * ND];
        ks[t] = acc;
    }
    __syncthreads();
    if (t < 64) {
        double acc = 0.0;
        const float* wq = Wq + (size_t)h * ND * ND + (size_t)t * ND;  // row t
        for (int e = 0; e < ND; ++e) acc += (double)wq[e] * ks[e];
        vs[t] = acc;
    }
    __syncthreads();
    const int l = blockIdx.y * 256 + t;
    const float* xp = xq + (((size_t)b * NL + l) * NH + h) * ND;
    double acc = 0.0;
#pragma unroll 8
    for (int d = 0; d < ND; ++d) acc += (double)xp[d] * vs[d];
    invden[(size_t)bh * NL + l] = (float)(1.0 / acc);
}

// ---------------- Kernel E: attn — T-J: ZERO-barrier, wave-private K streaming.
// Block = (bh, 256 l-rows). 8 waves, each with a PRIVATE 2x8KB K double-buffer
// (128KB LDS total). No s_barrier anywhere; per-wave counted vmcnt only.
// Waves free-run -> continuous store issue. Same MFMA chain order as R13.
__global__ __launch_bounds__(512, 1) void attn_kernel(const unsigned short* __restrict__ qbh,
                                                      const unsigned short* __restrict__ qbl,
                                                      const unsigned short* __restrict__ kbh,
                                                      const unsigned short* __restrict__ kbl,
                                                      const float* __restrict__ invden,
                                                      float* __restrict__ out) {
    __shared__ unsigned short kwbuf[8][2][2][32 * 64];  // [wave][buf][kh/kl][rows*e] = 128KB
    const int strip = blockIdx.x;        // 0..7
    const int bh = blockIdx.y;           // 0..31
    const int t = threadIdx.x;
    const int w = t >> 6, ln = t & 63;   // 8 waves
    const int fr = ln & 15, g = ln >> 4;
    const int swz = (fr & 7) << 4;
    const int cofs0 = (g << 4) ^ swz;
    const int cofs1 = (64 | (g << 4)) ^ swz;

    const size_t pan = (size_t)bh * NL * ND;
    const unsigned short* kh_p = kbh + pan;
    const unsigned short* kl_p = kbl + pan;
    const char* qh_pb = (const char*)(qbh + pan);
    const char* ql_pb = (const char*)(qbl + pan);
    const int lbase = strip * 256 + w * 32;

    // ---- q fragments (8 short8) + inv: loaded once, drained with one vmcnt(0)
    short8 qf00, qf01, qf10, qf11, qg00, qg01, qg10, qg11;
    {
        const size_t r0 = (size_t)(lbase + fr) * 128;
        const size_t r1 = (size_t)(lbase + 16 + fr) * 128;
        qf00 = *(const short8*)(qh_pb + r0 + cofs0);
        qf01 = *(const short8*)(qh_pb + r0 + cofs1);
        qf10 = *(const short8*)(ql_pb + r0 + cofs0);
        qf11 = *(const short8*)(ql_pb + r0 + cofs1);
        qg00 = *(const short8*)(qh_pb + r1 + cofs0);
        qg01 = *(const short8*)(qh_pb + r1 + cofs1);
        qg10 = *(const short8*)(ql_pb + r1 + cofs0);
        qg11 = *(const short8*)(ql_pb + r1 + cofs1);
    }
    const float inv0 = invden[(size_t)bh * NL + lbase + fr];
    const float inv1 = invden[(size_t)bh * NL + lbase + 16 + fr];
    asm volatile("s_waitcnt vmcnt(0)" ::: "memory");
    __builtin_amdgcn_sched_barrier(0);

    // chunk = 32 s-rows = kh 4KB + kl 4KB. One wave stages its own chunk: 8 gloads.
#define STAGE(c, buf)                                                                               \
    {                                                                                               \
        _Pragma("unroll")                                                                           \
        for (int u = 0; u < 4; ++u) {                                                               \
            __builtin_amdgcn_global_load_lds(                                                       \
                (const __attribute__((address_space(1))) unsigned int*)(kh_p + (size_t)(c) * 2048 + u * 512 + ln * 8), \
                (__attribute__((address_space(3))) unsigned int*)(&kwbuf[w][buf][0][u * 512]), 16, 0, 0); \
        }                                                                                           \
        _Pragma("unroll")                                                                           \
        for (int u = 0; u < 4; ++u) {                                                               \
            __builtin_amdgcn_global_load_lds(                                                       \
                (const __attribute__((address_space(1))) unsigned int*)(kl_p + (size_t)(c) * 2048 + u * 512 + ln * 8), \
                (__attribute__((address_space(3))) unsigned int*)(&kwbuf[w][buf][1][u * 512]), 16, 0, 0); \
        }                                                                                           \
    }

    // compute chunk c from buffer b; 4 frags (is x jl), 6-MFMA chain each (R13 order)
#define COMPUTE(c, b)                                                                               \
    {                                                                                               \
        const char* kh_b = (const char*)&kwbuf[w][b][0][0];                                         \
        const char* kl_b = (const char*)&kwbuf[w][b][1][0];                                         \
        _Pragma("unroll")                                                                           \
        for (int is = 0; is < 2; ++is) {                                                            \
            const int soff = (is * 16 + fr) * 128;                                                  \
            const short8 kh0 = *(const short8*)(kh_b + soff + cofs0);                               \
            const short8 kh1 = *(const short8*)(kh_b + soff + cofs1);                               \
            const short8 kl0 = *(const short8*)(kl_b + soff + cofs0);                               \
            const short8 kl1 = *(const short8*)(kl_b + soff + cofs1);                               \
            {                                                                                       \
                f32x4 a = (f32x4){0.f, 0.f, 0.f, 0.f};                                              \
                a = __builtin_amdgcn_mfma_f32_16x16x32_bf16(kh0, qf00, a, 0, 0, 0);                 \
                a = __builtin_amdgcn_mfma_f32_16x16x32_bf16(kh0, qf10, a, 0, 0, 0);                 \
                a = __builtin_amdgcn_mfma_f32_16x16x32_bf16(kl0, qf00, a, 0, 0, 0);                 \
                a = __builtin_amdgcn_mfma_f32_16x16x32_bf16(kh1, qf01, a, 0, 0, 0);                 \
                a = __builtin_amdgcn_mfma_f32_16x16x32_bf16(kh1, qf11, a, 0, 0, 0);                 \
                a = __builtin_amdgcn_mfma_f32_16x16x32_bf16(kl1, qf01, a, 0, 0, 0);                 \
                f32x4 vv = a;                                                                       \
                vv[0] *= inv0; vv[1] *= inv0; vv[2] *= inv0; vv[3] *= inv0;                         \
                *(f32x4*)(out + ((size_t)bh * NL + lbase + fr) * NL + (c) * 32 + is * 16 + g * 4) = vv; \
            }                                                                                       \
            {                                                                                       \
                f32x4 a = (f32x4){0.f, 0.f, 0.f, 0.f};                                              \
                a = __builtin_amdgcn_mfma_f32_16x16x32_bf16(kh0, qg00, a, 0, 0, 0);                 \
                a = __builtin_amdgcn_mfma_f32_16x16x32_bf16(kh0, qg10, a, 0, 0, 0);                 \
                a = __builtin_amdgcn_mfma_f32_16x16x32_bf16(kl0, qg00, a, 0, 0, 0);                 \
                a = __builtin_amdgcn_mfma_f32_16x16x32_bf16(kh1, qg01, a, 0, 0, 0);                 \
                a = __builtin_amdgcn_mfma_f32_16x16x32_bf16(kh1, qg11, a, 0, 0, 0);                 \
                a = __builtin_amdgcn_mfma_f32_16x16x32_bf16(kl1, qg01, a, 0, 0, 0);                 \
                f32x4 vv = a;                                                                       \
                vv[0] *= inv1; vv[1] *= inv1; vv[2] *= inv1; vv[3] *= inv1;                         \
                *(f32x4*)(out + ((size_t)bh * NL + lbase + 16 + fr) * NL + (c) * 32 + is * 16 + g * 4) = vv; \
            }                                                                                       \
        }                                                                                           \
    }

// lgkmcnt(0)+sched_barrier before re-staging a just-consumed buffer (rule #18)
#define LDS_FENCE()                                         \
    asm volatile("s_waitcnt lgkmcnt(0)" ::: "memory");      \
    __builtin_amdgcn_sched_barrier(0)

    STAGE(0, 0);
    STAGE(1, 1);

    // c = 0: outstanding = g0(8)+g1(8); need g0 -> vmcnt(8)
    asm volatile("s_waitcnt vmcnt(8)" ::: "memory");
    __builtin_amdgcn_sched_barrier(0);
    COMPUTE(0, 0);
    LDS_FENCE();
    STAGE(2, 0);

    // c = 1..61 steady state: outstanding = g_c(8)+s_{c-1}(4)+g_{c+1}(8);
    // need g_c -> vmcnt(12) (stores stay in flight, never drained)
    for (int c = 1; c <= 61; ++c) {
        asm volatile("s_waitcnt vmcnt(12)" ::: "memory");
        __builtin_amdgcn_sched_barrier(0);
        const int b = c & 1;
        COMPUTE(c, b);
        LDS_FENCE();
        STAGE(c + 2, b);
    }

    // c = 62: need g62 -> vmcnt(12); no stage
    asm volatile("s_waitcnt vmcnt(12)" ::: "memory");
    __builtin_amdgcn_sched_barrier(0);
    COMPUTE(62, 0);

    // c = 63: outstanding = g63(8)+s62(4); need g63 -> vmcnt(4)
    asm volatile("s_waitcnt vmcnt(4)" ::: "memory");
    __builtin_amdgcn_sched_barrier(0);
    COMPUTE(63, 1);

#undef STAGE
#undef COMPUTE
#undef LDS_FENCE
}

extern "C" void kernel_launch(void* const* d_in, const int* in_sizes, int n_in,
                              void* d_out, int out_size, void* d_ws, size_t ws_size,
                              hipStream_t stream) {
    const float* query = (const float*)d_in[0];  // [B,L,H,D]
    const float* key   = (const float*)d_in[1];  // [B,L,H,D]
    const float* Wq    = (const float*)d_in[2];  // [H,D,D]
    const float* Wk    = (const float*)d_in[3];  // [H,D,D]
    float* out = (float*)d_out;                  // [B,H,L,S]

    const size_t npan = (size_t)NB * NH * NL * ND;  // 4.19M elems
    char* ws = (char*)d_ws;
    unsigned short* qbh = (unsigned short*)(ws);
    unsigned short* qbl = (unsigned short*)(ws + 1 * npan * 2);
    unsigned short* kbh = (unsigned short*)(ws + 2 * npan * 2);
    unsigned short* kbl = (unsigned short*)(ws + 3 * npan * 2);
    double* part  = (double*)(ws + 4 * npan * 2);                  // 512*64 f64 = 256KB
    float* invden = (float*)(ws + 4 * npan * 2 + 262144);          // 32*2048 f32

    pre_kernel<<<1536, 256, 0, stream>>>(query, key, Wq, Wk, qbh, qbl, kbh, kbl, part);
    den_kernel<<<dim3(NB * NH, NL / 256), 256, 0, stream>>>(query, part, Wq, Wk, invden);
    attn_kernel<<<dim3(8, NB * NH), 512, 0, stream>>>(qbh, qbl, kbh, kbl, invden, out);
}

// Round 15
// 178.855 us; speedup vs baseline: 1.1832x; 1.0288x over previous
//
#include <hip/hip_runtime.h>
#include <stdint.h>

#define NB 2
#define NL 2048
#define NH 16
#define ND 64
// out: [B,H,L,S] f32, S = NL

typedef __attribute__((ext_vector_type(8))) short short8;
typedef __attribute__((ext_vector_type(4))) float f32x4;
typedef __attribute__((ext_vector_type(4))) unsigned short ushort4v;

__device__ __forceinline__ unsigned short f2bf_rne(float x) {
    union { float f; unsigned int u; } v; v.f = x;
    unsigned int r = v.u + 0x7fffu + ((v.u >> 16) & 1u);
    return (unsigned short)(r >> 16);
}
__device__ __forceinline__ float bf2f(unsigned short b) {
    union { unsigned int u; float f; } v; v.u = ((unsigned int)b) << 16;
    return v.f;
}

// ---------------- Kernel PRE: fused proj-q | proj-k | ksum partials (R13 verbatim)
__global__ __launch_bounds__(256) void pre_kernel(const float* __restrict__ query,
                                                  const float* __restrict__ key,
                                                  const float* __restrict__ Wq,
                                                  const float* __restrict__ Wk,
                                                  unsigned short* __restrict__ qbh,
                                                  unsigned short* __restrict__ qbl,
                                                  unsigned short* __restrict__ kbh,
                                                  unsigned short* __restrict__ kbl,
                                                  double* __restrict__ part) {
    __shared__ __align__(16) char lds_raw[16384 + 34816];  // Wlds | xs
    const int blk = blockIdx.x;
    const int t = threadIdx.x;

    if (blk < 1024) {
        const bool isq = blk < 512;
        const int pb = isq ? blk : blk - 512;
        const float* x = isq ? query : key;
        const float* W = isq ? Wq : Wk;
        unsigned short* ph = isq ? qbh : kbh;
        unsigned short* pl = isq ? qbl : kbl;
        float* Wlds = (float*)lds_raw;                 // [d][e] 16KB
        float* xs = (float*)(lds_raw + 16384);         // [r][d] stride 68

        const int lc = pb & 15;
        const int h = (pb >> 4) & 15;
        const int b = pb >> 8;
        const int l0 = lc * 128;

        {
            const float4* src = (const float4*)(W + (size_t)h * ND * ND);
#pragma unroll
            for (int i = 0; i < 4; ++i)
                ((float4*)Wlds)[t + 256 * i] = src[t + 256 * i];
        }
        {
#pragma unroll
            for (int i = 0; i < 8; ++i) {
                const int idx = t + 256 * i;  // 0..2047
                const int r = idx >> 4, c = idx & 15;
                const float4 v = *(const float4*)(x + (((size_t)b * NL + l0 + r) * NH + h) * ND + c * 4);
                *(float4*)&xs[r * 68 + c * 4] = v;
            }
        }
        __syncthreads();

        const int e4 = (t & 15) * 4;
        const int rg = t >> 4;  // 0..15
        float acc[8][4] = {};
        for (int d = 0; d < ND; ++d) {
            const float4 w4 = *(const float4*)&Wlds[d * ND + e4];
#pragma unroll
            for (int it = 0; it < 8; ++it) {
                const float xv = xs[(rg + it * 16) * 68 + d];
                acc[it][0] += xv * w4.x; acc[it][1] += xv * w4.y;
                acc[it][2] += xv * w4.z; acc[it][3] += xv * w4.w;
            }
        }

        unsigned short* phh = ph + ((size_t)(b * NH + h) * NL + l0) * ND;
        unsigned short* pll = pl + ((size_t)(b * NH + h) * NL + l0) * ND;
#pragma unroll
        for (int it = 0; it < 8; ++it) {
            const int r = rg + it * 16;
            const int ep = e4 ^ ((r & 7) << 3);
            ushort4v hv, lv;
#pragma unroll
            for (int j = 0; j < 4; ++j) {
                const unsigned short hb = f2bf_rne(acc[it][j]);
                hv[j] = hb;
                lv[j] = f2bf_rne(acc[it][j] - bf2f(hb));
            }
            *(ushort4v*)&phh[(size_t)r * ND + ep] = hv;
            *(ushort4v*)&pll[(size_t)r * ND + ep] = lv;
        }
    } else {
        double (*red)[64] = (double(*)[64])lds_raw;
        const int blk2 = blk - 1024;  // bh*16 + chunk
        const int chunk = blk2 & 15, bh = blk2 >> 4;
        const int b = bh >> 4, h = bh & 15;
        const int e = t & 63, sub = t >> 6;
        const float* base = key + ((size_t)b * NL * NH + h) * ND + e;
        double acc = 0.0;
        const int s0 = chunk * 128 + sub * 32;
        for (int s = s0; s < s0 + 32; ++s)
            acc += (double)base[(size_t)s * (NH * ND)];
        red[sub][e] = acc;
        __syncthreads();
        if (t < 64) {
            const double s2 = red[0][t] + red[1][t] + red[2][t] + red[3][t];
            part[(size_t)blk2 * 64 + t] = s2;
        }
    }
}

// ---------------- Kernel D: fused prep+den (R12 verbatim, proven)
__global__ __launch_bounds__(256) void den_kernel(const float* __restrict__ xq,
                                                  const double* __restrict__ part,
                                                  const float* __restrict__ Wq,
                                                  const float* __restrict__ Wk,
                                                  float* __restrict__ invden) {
    __shared__ double xs[ND], ks[ND], vs[ND];
    const int bh = blockIdx.x;
    const int b = bh >> 4, h = bh & 15;
    const int t = threadIdx.x;
    if (t < 64) {
        double a = 0.0;
#pragma unroll
        for (int c = 0; c < 16; ++c) a += part[((size_t)bh * 16 + c) * 64 + t];
        xs[t] = a;
    }
    __syncthreads();
    if (t < 64) {
        double acc = 0.0;
        const float* wk = Wk + (size_t)h * ND * ND + t;  // column t
        for (int d = 0; d < ND; ++d) acc += xs[d] * (double)wk[(size_t)d * ND];
        ks[t] = acc;
    }
    __syncthreads();
    if (t < 64) {
        double acc = 0.0;
        const float* wq = Wq + (size_t)h * ND * ND + (size_t)t * ND;  // row t
        for (int e = 0; e < ND; ++e) acc += (double)wq[e] * ks[e];
        vs[t] = acc;
    }
    __syncthreads();
    const int l = blockIdx.y * 256 + t;
    const float* xp = xq + (((size_t)b * NL + l) * NH + h) * ND;
    double acc = 0.0;
#pragma unroll 8
    for (int d = 0; d < ND; ++d) acc += (double)xp[d] * vs[d];
    invden[(size_t)bh * NL + l] = (float)(1.0 / acc);
}

// ---------------- Kernel E: attn — T-K build: R14 free-running streaming +
// LDS out-tile -> 256B-segment 1KB wave stores (4 segments/inst vs R14's 16).
// 8 waves, wave-private: K dbuf 2x4KB + out-tile 8KB = 16KB/wave = 128KB LDS.
// Zero block barriers; counted per-wave vmcnt only; stores never force-drained
// in steady state. Same MFMA chain order as R13/R14 -> bit-identical output.
__global__ __launch_bounds__(512, 1) void attn_kernel(const unsigned short* __restrict__ qbh,
                                                      const unsigned short* __restrict__ qbl,
                                                      const unsigned short* __restrict__ kbh,
                                                      const unsigned short* __restrict__ kbl,
                                                      const float* __restrict__ invden,
                                                      float* __restrict__ out) {
    __shared__ unsigned short kwbuf[8][2][2][1024];  // [wave][buf][kh/kl][16rows*64e] = 64KB
    __shared__ f32x4 obuf[8][512];                   // [wave][32rows * 16 swz 16B-chunks] = 64KB
    const int strip = blockIdx.x;        // 0..7
    const int bh = blockIdx.y;           // 0..31
    const int t = threadIdx.x;
    const int w = t >> 6, ln = t & 63;   // 8 waves
    const int fr = ln & 15, g = ln >> 4;
    const int swz = (fr & 7) << 4;
    const int cofs0 = (g << 4) ^ swz;
    const int cofs1 = (64 | (g << 4)) ^ swz;

    const size_t pan = (size_t)bh * NL * ND;
    const unsigned short* kh_p = kbh + pan;
    const unsigned short* kl_p = kbl + pan;
    const char* qh_pb = (const char*)(qbh + pan);
    const char* ql_pb = (const char*)(qbl + pan);
    const int lbase = strip * 256 + w * 32;

    // ---- q fragments (8 short8) + inv: loaded once
    short8 qf00, qf01, qf10, qf11, qg00, qg01, qg10, qg11;
    {
        const size_t r0 = (size_t)(lbase + fr) * 128;
        const size_t r1 = (size_t)(lbase + 16 + fr) * 128;
        qf00 = *(const short8*)(qh_pb + r0 + cofs0);
        qf01 = *(const short8*)(qh_pb + r0 + cofs1);
        qf10 = *(const short8*)(ql_pb + r0 + cofs0);
        qf11 = *(const short8*)(ql_pb + r0 + cofs1);
        qg00 = *(const short8*)(qh_pb + r1 + cofs0);
        qg01 = *(const short8*)(qh_pb + r1 + cofs1);
        qg10 = *(const short8*)(ql_pb + r1 + cofs0);
        qg11 = *(const short8*)(ql_pb + r1 + cofs1);
    }
    const float inv0 = invden[(size_t)bh * NL + lbase + fr];
    const float inv1 = invden[(size_t)bh * NL + lbase + 16 + fr];
    asm volatile("s_waitcnt vmcnt(0)" ::: "memory");
    __builtin_amdgcn_sched_barrier(0);

    // chunk = 16 s-rows: kh 2KB + kl 2KB. 4 gloads (1KB each) per chunk per wave.
#define STAGE(c, buf)                                                                               \
    {                                                                                               \
        _Pragma("unroll")                                                                           \
        for (int u = 0; u < 2; ++u) {                                                               \
            __builtin_amdgcn_global_load_lds(                                                       \
                (const __attribute__((address_space(1))) unsigned int*)(kh_p + (size_t)(c) * 1024 + u * 512 + ln * 8), \
                (__attribute__((address_space(3))) unsigned int*)(&kwbuf[w][buf][0][u * 512]), 16, 0, 0); \
        }                                                                                           \
        _Pragma("unroll")                                                                           \
        for (int u = 0; u < 2; ++u) {                                                               \
            __builtin_amdgcn_global_load_lds(                                                       \
                (const __attribute__((address_space(1))) unsigned int*)(kl_p + (size_t)(c) * 1024 + u * 512 + ln * 8), \
                (__attribute__((address_space(3))) unsigned int*)(&kwbuf[w][buf][1][u * 512]), 16, 0, 0); \
        }                                                                                           \
    }

#define WAITN(n)                                            \
    asm volatile("s_waitcnt vmcnt(" #n ")" ::: "memory");   \
    __builtin_amdgcn_sched_barrier(0)

#define LDS_FENCE()                                         \
    asm volatile("s_waitcnt lgkmcnt(0)" ::: "memory");      \
    __builtin_amdgcn_sched_barrier(0)

    // compute chunk (buf b, sub-chunk cc in group): 12 MFMA, results -> obuf (swizzled)
#define COMPUTE(b, cc)                                                                              \
    {                                                                                               \
        const char* kh_b = (const char*)&kwbuf[w][b][0][0];                                         \
        const char* kl_b = (const char*)&kwbuf[w][b][1][0];                                         \
        const int soff = fr * 128;                                                                  \
        const short8 kh0 = *(const short8*)(kh_b + soff + cofs0);                                   \
        const short8 kh1 = *(const short8*)(kh_b + soff + cofs1);                                   \
        const short8 kl0 = *(const short8*)(kl_b + soff + cofs0);                                   \
        const short8 kl1 = *(const short8*)(kl_b + soff + cofs1);                                   \
        {                                                                                           \
            f32x4 a = (f32x4){0.f, 0.f, 0.f, 0.f};                                                  \
            a = __builtin_amdgcn_mfma_f32_16x16x32_bf16(kh0, qf00, a, 0, 0, 0);                     \
            a = __builtin_amdgcn_mfma_f32_16x16x32_bf16(kh0, qf10, a, 0, 0, 0);                     \
            a = __builtin_amdgcn_mfma_f32_16x16x32_bf16(kl0, qf00, a, 0, 0, 0);                     \
            a = __builtin_amdgcn_mfma_f32_16x16x32_bf16(kh1, qf01, a, 0, 0, 0);                     \
            a = __builtin_amdgcn_mfma_f32_16x16x32_bf16(kh1, qf11, a, 0, 0, 0);                     \
            a = __builtin_amdgcn_mfma_f32_16x16x32_bf16(kl1, qf01, a, 0, 0, 0);                     \
            a[0] *= inv0; a[1] *= inv0; a[2] *= inv0; a[3] *= inv0;                                 \
            obuf[w][fr * 16 + (((cc) * 4 + g) ^ fr)] = a;                                           \
        }                                                                                           \
        {                                                                                           \
            f32x4 a = (f32x4){0.f, 0.f, 0.f, 0.f};                                                  \
            a = __builtin_amdgcn_mfma_f32_16x16x32_bf16(kh0, qg00, a, 0, 0, 0);                     \
            a = __builtin_amdgcn_mfma_f32_16x16x32_bf16(kh0, qg10, a, 0, 0, 0);                     \
            a = __builtin_amdgcn_mfma_f32_16x16x32_bf16(kl0, qg00, a, 0, 0, 0);                     \
            a = __builtin_amdgcn_mfma_f32_16x16x32_bf16(kh1, qg01, a, 0, 0, 0);                     \
            a = __builtin_amdgcn_mfma_f32_16x16x32_bf16(kh1, qg11, a, 0, 0, 0);                     \
            a = __builtin_amdgcn_mfma_f32_16x16x32_bf16(kl1, qg01, a, 0, 0, 0);                     \
            a[0] *= inv1; a[1] *= inv1; a[2] *= inv1; a[3] *= inv1;                                 \
            obuf[w][(16 + fr) * 16 + (((cc) * 4 + g) ^ fr)] = a;                                    \
        }                                                                                           \
    }

    // flush group c4: 8 ds_reads (swizzled, bank-floor) -> 8 x 1KB stores (4x256B segs)
#define FLUSH(c4)                                                                                   \
    {                                                                                               \
        f32x4 ov[8];                                                                                \
        _Pragma("unroll")                                                                           \
        for (int k8 = 0; k8 < 8; ++k8) {                                                            \
            const int row = k8 * 4 + (ln >> 4);                                                     \
            ov[k8] = obuf[w][row * 16 + ((ln & 15) ^ (row & 15))];                                  \
        }                                                                                           \
        LDS_FENCE();                                                                                \
        _Pragma("unroll")                                                                           \
        for (int k8 = 0; k8 < 8; ++k8) {                                                            \
            const int row = k8 * 4 + (ln >> 4);                                                     \
            *(f32x4*)(out + ((size_t)bh * NL + lbase + row) * NL + (c4) * 64 + (ln & 15) * 4) = ov[k8]; \
        }                                                                                           \
    }

    STAGE(0, 0);
    STAGE(1, 1);

    // ---- group 0 (c = 0..3): conservative N=4 (no flush yet in window)
    WAITN(4); COMPUTE(0, 0); LDS_FENCE(); STAGE(2, 0);
    WAITN(4); COMPUTE(1, 1); LDS_FENCE(); STAGE(3, 1);
    WAITN(4); COMPUTE(0, 2); LDS_FENCE(); STAGE(4, 0);
    WAITN(4); COMPUTE(1, 3); LDS_FENCE(); STAGE(5, 1);
    FLUSH(0);

    // ---- groups 1..30 steady state: N = [12,12,4,4]; stores never drained
    for (int c4 = 1; c4 <= 30; ++c4) {
        const int c = c4 * 4;
        WAITN(12); COMPUTE(0, 0); LDS_FENCE(); STAGE(c + 2, 0);
        WAITN(12); COMPUTE(1, 1); LDS_FENCE(); STAGE(c + 3, 1);
        WAITN(4);  COMPUTE(0, 2); LDS_FENCE(); STAGE(c + 4, 0);
        WAITN(4);  COMPUTE(1, 3); LDS_FENCE(); STAGE(c + 5, 1);
        FLUSH(c4);
    }

    // ---- group 31 (c = 124..127): epilogue, no stage past 127
    WAITN(12); COMPUTE(0, 0); LDS_FENCE(); STAGE(126, 0);
    WAITN(12); COMPUTE(1, 1); LDS_FENCE(); STAGE(127, 1);
    WAITN(4);  COMPUTE(0, 2); LDS_FENCE();
    WAITN(0);  COMPUTE(1, 3); LDS_FENCE();
    FLUSH(31);

#undef STAGE
#undef WAITN
#undef LDS_FENCE
#undef COMPUTE
#undef FLUSH
}

extern "C" void kernel_launch(void* const* d_in, const int* in_sizes, int n_in,
                              void* d_out, int out_size, void* d_ws, size_t ws_size,
                              hipStream_t stream) {
    const float* query = (const float*)d_in[0];  // [B,L,H,D]
    const float* key   = (const float*)d_in[1];  // [B,L,H,D]
    const float* Wq    = (const float*)d_in[2];  // [H,D,D]
    const float* Wk    = (const float*)d_in[3];  // [H,D,D]
    float* out = (float*)d_out;                  // [B,H,L,S]

    const size_t npan = (size_t)NB * NH * NL * ND;  // 4.19M elems
    char* ws = (char*)d_ws;
    unsigned short* qbh = (unsigned short*)(ws);
    unsigned short* qbl = (unsigned short*)(ws + 1 * npan * 2);
    unsigned short* kbh = (unsigned short*)(ws + 2 * npan * 2);
    unsigned short* kbl = (unsigned short*)(ws + 3 * npan * 2);
    double* part  = (double*)(ws + 4 * npan * 2);                  // 512*64 f64 = 256KB
    float* invden = (float*)(ws + 4 * npan * 2 + 262144);          // 32*2048 f32

    pre_kernel<<<1536, 256, 0, stream>>>(query, key, Wq, Wk, qbh, qbl, kbh, kbl, part);
    den_kernel<<<dim3(NB * NH, NL / 256), 256, 0, stream>>>(query, part, Wq, Wk, invden);
    attn_kernel<<<dim3(8, NB * NH), 512, 0, stream>>>(qbh, qbl, kbh, kbl, invden, out);
}

// Round 16
// 175.699 us; speedup vs baseline: 1.2044x; 1.0180x over previous
//
#include <hip/hip_runtime.h>
#include <stdint.h>

#define NB 2
#define NL 2048
#define NH 16
#define ND 64
// out: [B,H,L,S] f32, S = NL

typedef __attribute__((ext_vector_type(8))) short short8;
typedef __attribute__((ext_vector_type(4))) float f32x4;
typedef __attribute__((ext_vector_type(4))) unsigned short ushort4v;

__device__ __forceinline__ unsigned short f2bf_rne(float x) {
    union { float f; unsigned int u; } v; v.f = x;
    unsigned int r = v.u + 0x7fffu + ((v.u >> 16) & 1u);
    return (unsigned short)(r >> 16);
}
__device__ __forceinline__ float bf2f(unsigned short b) {
    union { unsigned int u; float f; } v; v.u = ((unsigned int)b) << 16;
    return v.f;
}

// ---------------- Kernel PRE: fused proj-q | proj-k | ksum partials (R13 verbatim)
__global__ __launch_bounds__(256) void pre_kernel(const float* __restrict__ query,
                                                  const float* __restrict__ key,
                                                  const float* __restrict__ Wq,
                                                  const float* __restrict__ Wk,
                                                  unsigned short* __restrict__ qbh,
                                                  unsigned short* __restrict__ qbl,
                                                  unsigned short* __restrict__ kbh,
                                                  unsigned short* __restrict__ kbl,
                                                  double* __restrict__ part) {
    __shared__ __align__(16) char lds_raw[16384 + 34816];  // Wlds | xs
    const int blk = blockIdx.x;
    const int t = threadIdx.x;

    if (blk < 1024) {
        const bool isq = blk < 512;
        const int pb = isq ? blk : blk - 512;
        const float* x = isq ? query : key;
        const float* W = isq ? Wq : Wk;
        unsigned short* ph = isq ? qbh : kbh;
        unsigned short* pl = isq ? qbl : kbl;
        float* Wlds = (float*)lds_raw;                 // [d][e] 16KB
        float* xs = (float*)(lds_raw + 16384);         // [r][d] stride 68

        const int lc = pb & 15;
        const int h = (pb >> 4) & 15;
        const int b = pb >> 8;
        const int l0 = lc * 128;

        {
            const float4* src = (const float4*)(W + (size_t)h * ND * ND);
#pragma unroll
            for (int i = 0; i < 4; ++i)
                ((float4*)Wlds)[t + 256 * i] = src[t + 256 * i];
        }
        {
#pragma unroll
            for (int i = 0; i < 8; ++i) {
                const int idx = t + 256 * i;  // 0..2047
                const int r = idx >> 4, c = idx & 15;
                const float4 v = *(const float4*)(x + (((size_t)b * NL + l0 + r) * NH + h) * ND + c * 4);
                *(float4*)&xs[r * 68 + c * 4] = v;
            }
        }
        __syncthreads();

        const int e4 = (t & 15) * 4;
        const int rg = t >> 4;  // 0..15
        float acc[8][4] = {};
        for (int d = 0; d < ND; ++d) {
            const float4 w4 = *(const float4*)&Wlds[d * ND + e4];
#pragma unroll
            for (int it = 0; it < 8; ++it) {
                const float xv = xs[(rg + it * 16) * 68 + d];
                acc[it][0] += xv * w4.x; acc[it][1] += xv * w4.y;
                acc[it][2] += xv * w4.z; acc[it][3] += xv * w4.w;
            }
        }

        unsigned short* phh = ph + ((size_t)(b * NH + h) * NL + l0) * ND;
        unsigned short* pll = pl + ((size_t)(b * NH + h) * NL + l0) * ND;
#pragma unroll
        for (int it = 0; it < 8; ++it) {
            const int r = rg + it * 16;
            const int ep = e4 ^ ((r & 7) << 3);
            ushort4v hv, lv;
#pragma unroll
            for (int j = 0; j < 4; ++j) {
                const unsigned short hb = f2bf_rne(acc[it][j]);
                hv[j] = hb;
                lv[j] = f2bf_rne(acc[it][j] - bf2f(hb));
            }
            *(ushort4v*)&phh[(size_t)r * ND + ep] = hv;
            *(ushort4v*)&pll[(size_t)r * ND + ep] = lv;
        }
    } else {
        double (*red)[64] = (double(*)[64])lds_raw;
        const int blk2 = blk - 1024;  // bh*16 + chunk
        const int chunk = blk2 & 15, bh = blk2 >> 4;
        const int b = bh >> 4, h = bh & 15;
        const int e = t & 63, sub = t >> 6;
        const float* base = key + ((size_t)b * NL * NH + h) * ND + e;
        double acc = 0.0;
        const int s0 = chunk * 128 + sub * 32;
        for (int s = s0; s < s0 + 32; ++s)
            acc += (double)base[(size_t)s * (NH * ND)];
        red[sub][e] = acc;
        __syncthreads();
        if (t < 64) {
            const double s2 = red[0][t] + red[1][t] + red[2][t] + red[3][t];
            part[(size_t)blk2 * 64 + t] = s2;
        }
    }
}

// ---------------- Kernel C: reduce partials; v[b,h,d] = Wq . (Wk^T . xsum)  (f64)
// (revived from R13 — tiny, 32 blocks; identical arithmetic order)
__global__ __launch_bounds__(64) void prep_kernel(const double* __restrict__ part,
                                                  const float* __restrict__ Wq,
                                                  const float* __restrict__ Wk,
                                                  double* __restrict__ v) {
    __shared__ double xs[ND], ks[ND];
    const int bh = blockIdx.x;
    const int h = bh & 15;
    const int t = threadIdx.x;  // 0..63
    {
        double a = 0.0;
#pragma unroll
        for (int c = 0; c < 16; ++c) a += part[((size_t)bh * 16 + c) * 64 + t];
        xs[t] = a;
    }
    __syncthreads();
    {
        double acc = 0.0;
        const float* wk = Wk + (size_t)h * ND * ND + t;  // column t
        for (int d = 0; d < ND; ++d) acc += xs[d] * (double)wk[(size_t)d * ND];
        ks[t] = acc;
    }
    __syncthreads();
    {
        double acc = 0.0;
        const float* wq = Wq + (size_t)h * ND * ND + (size_t)t * ND;  // row t
        for (int e = 0; e < ND; ++e) acc += (double)wq[e] * ks[e];
        v[(size_t)bh * ND + t] = acc;
    }
}

// ---------------- Kernel E: attn — R15 body + fused invden prologue.
// Prologue: lanes<32 of each wave compute invden for the wave's 32 rows in f64
// (IDENTICAL d=0..63 serial order as old den_kernel -> bit-identical output),
// broadcast via small LDS. Body: R15 verbatim (T-K 256B-segment flush build).
__global__ __launch_bounds__(512, 1) void attn_kernel(const float* __restrict__ query,
                                                      const double* __restrict__ vden,
                                                      const unsigned short* __restrict__ qbh,
                                                      const unsigned short* __restrict__ qbl,
                                                      const unsigned short* __restrict__ kbh,
                                                      const unsigned short* __restrict__ kbl,
                                                      float* __restrict__ out) {
    __shared__ unsigned short kwbuf[8][2][2][1024];  // [wave][buf][kh/kl][16rows*64e] = 64KB
    __shared__ f32x4 obuf[8][512];                   // [wave][32rows * 16 swz 16B-chunks] = 64KB
    __shared__ float invs[256];                      // per-block invden slab
    const int strip = blockIdx.x;        // 0..7
    const int bh = blockIdx.y;           // 0..31
    const int b = bh >> 4, h = bh & 15;
    const int t = threadIdx.x;
    const int w = t >> 6, ln = t & 63;   // 8 waves
    const int fr = ln & 15, g = ln >> 4;
    const int swz = (fr & 7) << 4;
    const int cofs0 = (g << 4) ^ swz;
    const int cofs1 = (64 | (g << 4)) ^ swz;

    const size_t pan = (size_t)bh * NL * ND;
    const unsigned short* kh_p = kbh + pan;
    const unsigned short* kl_p = kbl + pan;
    const char* qh_pb = (const char*)(qbh + pan);
    const char* ql_pb = (const char*)(qbl + pan);
    const int lbase = strip * 256 + w * 32;

    // ---- fused den prologue: lane r<32 computes invden row lbase+r (exact f64,
    // same serial order as the old den_kernel)
    {
        if (ln < 32) {
            const int l = lbase + ln;
            const float* xp = query + (((size_t)b * NL + l) * NH + h) * ND;
            const double* vp = vden + (size_t)bh * ND;
            double acc = 0.0;
#pragma unroll 8
            for (int d = 0; d < ND; ++d) acc += (double)xp[d] * vp[d];
            invs[w * 32 + ln] = (float)(1.0 / acc);
        }
    }
    // no block barrier needed: each wave reads only its own 32 slots below.

    // ---- q fragments (8 short8): loaded once
    short8 qf00, qf01, qf10, qf11, qg00, qg01, qg10, qg11;
    {
        const size_t r0 = (size_t)(lbase + fr) * 128;
        const size_t r1 = (size_t)(lbase + 16 + fr) * 128;
        qf00 = *(const short8*)(qh_pb + r0 + cofs0);
        qf01 = *(const short8*)(qh_pb + r0 + cofs1);
        qf10 = *(const short8*)(ql_pb + r0 + cofs0);
        qf11 = *(const short8*)(ql_pb + r0 + cofs1);
        qg00 = *(const short8*)(qh_pb + r1 + cofs0);
        qg01 = *(const short8*)(qh_pb + r1 + cofs1);
        qg10 = *(const short8*)(ql_pb + r1 + cofs0);
        qg11 = *(const short8*)(ql_pb + r1 + cofs1);
    }
    const float inv0 = invs[w * 32 + fr];
    const float inv1 = invs[w * 32 + 16 + fr];
    asm volatile("s_waitcnt vmcnt(0)" ::: "memory");
    __builtin_amdgcn_sched_barrier(0);

#define STAGE(c, buf)                                                                               \
    {                                                                                               \
        _Pragma("unroll")                                                                           \
        for (int u = 0; u < 2; ++u) {                                                               \
            __builtin_amdgcn_global_load_lds(                                                       \
                (const __attribute__((address_space(1))) unsigned int*)(kh_p + (size_t)(c) * 1024 + u * 512 + ln * 8), \
                (__attribute__((address_space(3))) unsigned int*)(&kwbuf[w][buf][0][u * 512]), 16, 0, 0); \
        }                                                                                           \
        _Pragma("unroll")                                                                           \
        for (int u = 0; u < 2; ++u) {                                                               \
            __builtin_amdgcn_global_load_lds(                                                       \
                (const __attribute__((address_space(1))) unsigned int*)(kl_p + (size_t)(c) * 1024 + u * 512 + ln * 8), \
                (__attribute__((address_space(3))) unsigned int*)(&kwbuf[w][buf][1][u * 512]), 16, 0, 0); \
        }                                                                                           \
    }

#define WAITN(n)                                            \
    asm volatile("s_waitcnt vmcnt(" #n ")" ::: "memory");   \
    __builtin_amdgcn_sched_barrier(0)

#define LDS_FENCE()                                         \
    asm volatile("s_waitcnt lgkmcnt(0)" ::: "memory");      \
    __builtin_amdgcn_sched_barrier(0)

#define COMPUTE(b, cc)                                                                              \
    {                                                                                               \
        const char* kh_b = (const char*)&kwbuf[w][b][0][0];                                         \
        const char* kl_b = (const char*)&kwbuf[w][b][1][0];                                         \
        const int soff = fr * 128;                                                                  \
        const short8 kh0 = *(const short8*)(kh_b + soff + cofs0);                                   \
        const short8 kh1 = *(const short8*)(kh_b + soff + cofs1);                                   \
        const short8 kl0 = *(const short8*)(kl_b + soff + cofs0);                                   \
        const short8 kl1 = *(const short8*)(kl_b + soff + cofs1);                                   \
        {                                                                                           \
            f32x4 a = (f32x4){0.f, 0.f, 0.f, 0.f};                                                  \
            a = __builtin_amdgcn_mfma_f32_16x16x32_bf16(kh0, qf00, a, 0, 0, 0);                     \
            a = __builtin_amdgcn_mfma_f32_16x16x32_bf16(kh0, qf10, a, 0, 0, 0);                     \
            a = __builtin_amdgcn_mfma_f32_16x16x32_bf16(kl0, qf00, a, 0, 0, 0);                     \
            a = __builtin_amdgcn_mfma_f32_16x16x32_bf16(kh1, qf01, a, 0, 0, 0);                     \
            a = __builtin_amdgcn_mfma_f32_16x16x32_bf16(kh1, qf11, a, 0, 0, 0);                     \
            a = __builtin_amdgcn_mfma_f32_16x16x32_bf16(kl1, qf01, a, 0, 0, 0);                     \
            a[0] *= inv0; a[1] *= inv0; a[2] *= inv0; a[3] *= inv0;                                 \
            obuf[w][fr * 16 + (((cc) * 4 + g) ^ fr)] = a;                                           \
        }                                                                                           \
        {                                                                                           \
            f32x4 a = (f32x4){0.f, 0.f, 0.f, 0.f};                                                  \
            a = __builtin_amdgcn_mfma_f32_16x16x32_bf16(kh0, qg00, a, 0, 0, 0);                     \
            a = __builtin_amdgcn_mfma_f32_16x16x32_bf16(kh0, qg10, a, 0, 0, 0);                     \
            a = __builtin_amdgcn_mfma_f32_16x16x32_bf16(kl0, qg00, a, 0, 0, 0);                     \
            a = __builtin_amdgcn_mfma_f32_16x16x32_bf16(kh1, qg01, a, 0, 0, 0);                     \
            a = __builtin_amdgcn_mfma_f32_16x16x32_bf16(kh1, qg11, a, 0, 0, 0);                     \
            a = __builtin_amdgcn_mfma_f32_16x16x32_bf16(kl1, qg01, a, 0, 0, 0);                     \
            a[0] *= inv1; a[1] *= inv1; a[2] *= inv1; a[3] *= inv1;                                 \
            obuf[w][(16 + fr) * 16 + (((cc) * 4 + g) ^ fr)] = a;                                    \
        }                                                                                           \
    }

#define FLUSH(c4)                                                                                   \
    {                                                                                               \
        f32x4 ov[8];                                                                                \
        _Pragma("unroll")                                                                           \
        for (int k8 = 0; k8 < 8; ++k8) {                                                            \
            const int row = k8 * 4 + (ln >> 4);                                                     \
            ov[k8] = obuf[w][row * 16 + ((ln & 15) ^ (row & 15))];                                  \
        }                                                                                           \
        LDS_FENCE();                                                                                \
        _Pragma("unroll")                                                                           \
        for (int k8 = 0; k8 < 8; ++k8) {                                                            \
            const int row = k8 * 4 + (ln >> 4);                                                     \
            *(f32x4*)(out + ((size_t)bh * NL + lbase + row) * NL + (c4) * 64 + (ln & 15) * 4) = ov[k8]; \
        }                                                                                           \
    }

    STAGE(0, 0);
    STAGE(1, 1);

    // ---- group 0 (c = 0..3): conservative N=4
    WAITN(4); COMPUTE(0, 0); LDS_FENCE(); STAGE(2, 0);
    WAITN(4); COMPUTE(1, 1); LDS_FENCE(); STAGE(3, 1);
    WAITN(4); COMPUTE(0, 2); LDS_FENCE(); STAGE(4, 0);
    WAITN(4); COMPUTE(1, 3); LDS_FENCE(); STAGE(5, 1);
    FLUSH(0);

    // ---- groups 1..30 steady state: N = [12,12,4,4]; stores never drained
    for (int c4 = 1; c4 <= 30; ++c4) {
        const int c = c4 * 4;
        WAITN(12); COMPUTE(0, 0); LDS_FENCE(); STAGE(c + 2, 0);
        WAITN(12); COMPUTE(1, 1); LDS_FENCE(); STAGE(c + 3, 1);
        WAITN(4);  COMPUTE(0, 2); LDS_FENCE(); STAGE(c + 4, 0);
        WAITN(4);  COMPUTE(1, 3); LDS_FENCE(); STAGE(c + 5, 1);
        FLUSH(c4);
    }

    // ---- group 31 (c = 124..127): epilogue
    WAITN(12); COMPUTE(0, 0); LDS_FENCE(); STAGE(126, 0);
    WAITN(12); COMPUTE(1, 1); LDS_FENCE(); STAGE(127, 1);
    WAITN(4);  COMPUTE(0, 2); LDS_FENCE();
    WAITN(0);  COMPUTE(1, 3); LDS_FENCE();
    FLUSH(31);

#undef STAGE
#undef WAITN
#undef LDS_FENCE
#undef COMPUTE
#undef FLUSH
}

extern "C" void kernel_launch(void* const* d_in, const int* in_sizes, int n_in,
                              void* d_out, int out_size, void* d_ws, size_t ws_size,
                              hipStream_t stream) {
    const float* query = (const float*)d_in[0];  // [B,L,H,D]
    const float* key   = (const float*)d_in[1];  // [B,L,H,D]
    const float* Wq    = (const float*)d_in[2];  // [H,D,D]
    const float* Wk    = (const float*)d_in[3];  // [H,D,D]
    float* out = (float*)d_out;                  // [B,H,L,S]

    const size_t npan = (size_t)NB * NH * NL * ND;  // 4.19M elems
    char* ws = (char*)d_ws;
    unsigned short* qbh = (unsigned short*)(ws);
    unsigned short* qbl = (unsigned short*)(ws + 1 * npan * 2);
    unsigned short* kbh = (unsigned short*)(ws + 2 * npan * 2);
    unsigned short* kbl = (unsigned short*)(ws + 3 * npan * 2);
    double* part  = (double*)(ws + 4 * npan * 2);                  // 512*64 f64 = 256KB
    double* vden  = (double*)(ws + 4 * npan * 2 + 262144);         // 32*64 f64

    pre_kernel<<<1536, 256, 0, stream>>>(query, key, Wq, Wk, qbh, qbl, kbh, kbl, part);
    prep_kernel<<<NB * NH, 64, 0, stream>>>(part, Wq, Wk, vden);
    attn_kernel<<<dim3(8, NB * NH), 512, 0, stream>>>(query, vden, qbh, qbl, kbh, kbl, out);
}